// Round 7
// baseline (267.707 us; speedup 1.0000x reference)
//
#include <hip/hip_runtime.h>

// Problem constants (fixed by setup_inputs)
#define BQ   4
#define CQ   2
#define EQ   256
#define LQ   16000
#define WQ   40
#define STEP 20
#define TQ   ((LQ - 1) * STEP + WQ)   // 320020
#define TLF  255                      // frame pitch per block (256 frames computed)
#define OWN  (TLF * STEP)             // 5100 owned output samples per block
#define NBX  63                       // 63 * 5100 = 321300 >= 320020
#define SPAN (TLF * STEP + WQ)        // 5140 floats per accumulation copy
#define NH   4                        // e-quarters (one per wave)
#define EH   (EQ / NH)                // 64 e's per wave
#define FPT  4                        // frames per thread

// Pre-kernel: transpose basis [W][E] -> wsT [E][W] fp32 so the main kernel can
// stage it into LDS with coalesced, conflict-free copies.
__global__ void transpose_basis_kernel(const float* __restrict__ basis,
                                       float* __restrict__ wsT) {
    int i = blockIdx.x * 256 + threadIdx.x;
    if (i < EQ * WQ) {
        int e = i / WQ;
        int w = i - e * WQ;
        wsT[i] = basis[w * EQ + e];
    }
}

// One block: 256 threads = 4 waves. Wave wv owns e-quarter [wv*64, wv*64+64).
// Thread (wv, lane) computes FPT=4 frames idx = 64*j + lane,
// f = 255*bx - 1 + idx, acc[j][w] += mix*mask*basisT[e][w].
// K-loop uses an explicit depth-2 rotating prefetch of the 8 m/k values so
// ~16 loads stay in flight per wave (R6 failure: __launch_bounds__(256,2)
// capped VGPRs at 128 < 160 accs -> spill + zero prefetch headroom).
// Epilogue: overlap-add into 2 LDS copies (wave-pair each), 4 serialized
// phases -> no atomics (measured conflict-free in R6). basisT LDS is unioned.
__global__ __launch_bounds__(256) void decoder_kernel(
    const float* __restrict__ mix,    // [B,E,L]
    const float* __restrict__ mask,   // [B,C,E,L]
    const float* __restrict__ wsT,    // [E,W] transposed basis
    float* __restrict__ out)          // [B,C,T]
{
    __shared__ __align__(16) float smem[2 * SPAN];  // 41.1 KB; basisT aliases [0,10240)

    const int tid  = threadIdx.x;
    const int lane = tid & 63;
    const int wv   = tid >> 6;        // e-quarter
    const int bx   = blockIdx.x;
    const int b    = blockIdx.y;
    const int c    = blockIdx.z;

    // Stage basisT = wsT into LDS (coalesced global, conflict-free LDS).
    float* basisT = smem;
    for (int i = tid; i < EQ * WQ; i += 256) basisT[i] = wsT[i];
    __syncthreads();

    // Frame indices and validity for the FPT frames of this thread.
    int   fc[FPT];
    float valid[FPT];
#pragma unroll
    for (int j = 0; j < FPT; ++j) {
        int f = TLF * bx - 1 + (j * 64 + lane);
        fc[j]    = min(max(f, 0), LQ - 1);
        valid[j] = (f >= 0 && f < LQ) ? 1.0f : 0.0f;
    }

    float4 acc[FPT][WQ / 4];
#pragma unroll
    for (int j = 0; j < FPT; ++j)
#pragma unroll
        for (int t = 0; t < WQ / 4; ++t) acc[j][t] = make_float4(0.f, 0.f, 0.f, 0.f);

    const float* mp = mix  + ((size_t)b * EQ + wv * EH) * LQ;
    const float* kp = mask + (((size_t)(b * CQ + c)) * EQ + wv * EH) * LQ;

    // Depth-2 rotating prefetch stages.
    float mS[2][FPT], kS[2][FPT];
#pragma unroll
    for (int j = 0; j < FPT; ++j) {
        mS[0][j] = mp[(size_t)0 * LQ + fc[j]];
        kS[0][j] = kp[(size_t)0 * LQ + fc[j]];
        mS[1][j] = mp[(size_t)1 * LQ + fc[j]];
        kS[1][j] = kp[(size_t)1 * LQ + fc[j]];
    }

    for (int eo = 0; eo < EH; eo += 2) {
        // ---- consume stage 0 (e = eo), refill with e = eo+2 ----
        {
            float s[FPT];
#pragma unroll
            for (int j = 0; j < FPT; ++j) s[j] = mS[0][j] * kS[0][j] * valid[j];
            const int en = min(eo + 2, EH - 1);   // branch-free clamp (dup row, unused)
#pragma unroll
            for (int j = 0; j < FPT; ++j) {
                mS[0][j] = mp[(size_t)en * LQ + fc[j]];
                kS[0][j] = kp[(size_t)en * LQ + fc[j]];
            }
            const float4* bt = (const float4*)&basisT[(wv * EH + eo) * WQ];
#pragma unroll
            for (int t = 0; t < WQ / 4; ++t) {
                float4 bv = bt[t];   // wave-uniform broadcast read
#pragma unroll
                for (int j = 0; j < FPT; ++j) {
                    acc[j][t].x = fmaf(s[j], bv.x, acc[j][t].x);
                    acc[j][t].y = fmaf(s[j], bv.y, acc[j][t].y);
                    acc[j][t].z = fmaf(s[j], bv.z, acc[j][t].z);
                    acc[j][t].w = fmaf(s[j], bv.w, acc[j][t].w);
                }
            }
        }
        // ---- consume stage 1 (e = eo+1), refill with e = eo+3 ----
        {
            float s[FPT];
#pragma unroll
            for (int j = 0; j < FPT; ++j) s[j] = mS[1][j] * kS[1][j] * valid[j];
            const int en = min(eo + 3, EH - 1);
#pragma unroll
            for (int j = 0; j < FPT; ++j) {
                mS[1][j] = mp[(size_t)en * LQ + fc[j]];
                kS[1][j] = kp[(size_t)en * LQ + fc[j]];
            }
            const float4* bt = (const float4*)&basisT[(wv * EH + eo + 1) * WQ];
#pragma unroll
            for (int t = 0; t < WQ / 4; ++t) {
                float4 bv = bt[t];
#pragma unroll
                for (int j = 0; j < FPT; ++j) {
                    acc[j][t].x = fmaf(s[j], bv.x, acc[j][t].x);
                    acc[j][t].y = fmaf(s[j], bv.y, acc[j][t].y);
                    acc[j][t].z = fmaf(s[j], bv.z, acc[j][t].z);
                    acc[j][t].w = fmaf(s[j], bv.w, acc[j][t].w);
                }
            }
        }
    }
    __syncthreads();   // basisT dead; smem becomes 2 accumulation copies

    // Overlap-add. Copy cp = wv>>1 accumulates waves {2cp, 2cp+1}.
    // 4 serialized phases (wave-parity x lane-parity); within a phase all
    // [20*idx, 20*idx+40) ranges are disjoint. Even-idx ranges tile [0,5120)
    // exactly -> phase 0 is a plain store. Tail [5120,5140) write-only.
    float4* outC = (float4*)(smem + (wv >> 1) * SPAN);
    const int hp = wv & 1;
    const int lp = lane & 1;

    if (hp == 0 && lp == 0) {
#pragma unroll
        for (int j = 0; j < FPT; ++j) {
            float4* p = (float4*)((float*)outC + (j * 64 + lane) * STEP);
#pragma unroll
            for (int t = 0; t < WQ / 4; ++t) p[t] = acc[j][t];
        }
    }
    __syncthreads();
    if (hp == 0 && lp == 1) {
#pragma unroll
        for (int j = 0; j < FPT; ++j) {
            float4* p = (float4*)((float*)outC + (j * 64 + lane) * STEP);
#pragma unroll
            for (int t = 0; t < WQ / 4; ++t) {
                float4 v = p[t];
                v.x += acc[j][t].x; v.y += acc[j][t].y;
                v.z += acc[j][t].z; v.w += acc[j][t].w;
                p[t] = v;
            }
        }
    }
    __syncthreads();
    if (hp == 1 && lp == 0) {
#pragma unroll
        for (int j = 0; j < FPT; ++j) {
            float4* p = (float4*)((float*)outC + (j * 64 + lane) * STEP);
#pragma unroll
            for (int t = 0; t < WQ / 4; ++t) {
                float4 v = p[t];
                v.x += acc[j][t].x; v.y += acc[j][t].y;
                v.z += acc[j][t].z; v.w += acc[j][t].w;
                p[t] = v;
            }
        }
    }
    __syncthreads();
    if (hp == 1 && lp == 1) {
#pragma unroll
        for (int j = 0; j < FPT; ++j) {
            float4* p = (float4*)((float*)outC + (j * 64 + lane) * STEP);
#pragma unroll
            for (int t = 0; t < WQ / 4; ++t) {
                float4 v = p[t];
                v.x += acc[j][t].x; v.y += acc[j][t].y;
                v.z += acc[j][t].z; v.w += acc[j][t].w;
                p[t] = v;
            }
        }
    }
    __syncthreads();

    // Store owned span: t = 5100*bx + i  <->  copy0[20+i] + copy1[20+i]
    const size_t ob = ((size_t)b * CQ + c) * TQ + (size_t)OWN * bx;
    for (int i = tid; i < OWN; i += 256) {
        const long t = (long)OWN * bx + i;
        if (t < (long)TQ) {
            out[ob + i] = smem[STEP + i] + smem[SPAN + STEP + i];
        }
    }
}

extern "C" void kernel_launch(void* const* d_in, const int* in_sizes, int n_in,
                              void* d_out, int out_size, void* d_ws, size_t ws_size,
                              hipStream_t stream) {
    const float* mix   = (const float*)d_in[0];
    const float* mask  = (const float*)d_in[1];
    const float* basis = (const float*)d_in[2];
    float* out = (float*)d_out;
    float* wsT = (float*)d_ws;   // needs EQ*WQ*4 = 40960 bytes

    transpose_basis_kernel<<<dim3((EQ * WQ + 255) / 256), 256, 0, stream>>>(basis, wsT);

    dim3 grid(NBX, BQ, CQ);
    decoder_kernel<<<grid, 256, 0, stream>>>(mix, mask, wsT, out);
}